// Round 7
// baseline (722.490 us; speedup 1.0000x reference)
//
#include <hip/hip_runtime.h>
#include <hip/hip_bf16.h>
#include <stdint.h>

// Problem constants
constexpr int S = 2048;
constexpr int B = 4;
constexpr int D = 1024;
constexpr int H = 16;
constexpr int F = 4096;
constexpr int DH = 64;            // D / H
constexpr int N = S * B;          // 8192 rows
constexpr int QKVS = 3 * D;       // qkv row stride

typedef __attribute__((ext_vector_type(8))) short  bf16x8;
typedef __attribute__((ext_vector_type(4))) float  floatx4;

__device__ __forceinline__ unsigned short f2bf(float f) {
    __hip_bfloat16 h = __float2bfloat16(f);
    return __builtin_bit_cast(unsigned short, h);
}
__device__ __forceinline__ uint32_t pack_bf2_fast(float a, float b) {
    uint32_t ua = __builtin_bit_cast(uint32_t, a) + 0x8000u;
    uint32_t ub = __builtin_bit_cast(uint32_t, b) + 0x8000u;
    return (ua >> 16) | (ub & 0xffff0000u);
}
__device__ __forceinline__ void glds16(const unsigned short* g, unsigned short* l) {
    __builtin_amdgcn_global_load_lds((__attribute__((address_space(1))) void*)(g),
                                     (__attribute__((address_space(3))) void*)(l),
                                     16, 0, 0);
}

// ---------------------------------------------------------------------------
// Weight convert + transpose: src fp32 [K][M] -> dst bf16 [M][K]
// ---------------------------------------------------------------------------
__global__ __launch_bounds__(256) void convert_transpose(
    const float* __restrict__ src, unsigned short* __restrict__ dst, int K, int M) {
    __shared__ float tile[32][33];
    const int m0 = blockIdx.x * 32;
    const int k0 = blockIdx.y * 32;
    const int tx = threadIdx.x;
    const int ty = threadIdx.y;
    #pragma unroll
    for (int i = 0; i < 32; i += 8)
        tile[ty + i][tx] = src[(size_t)(k0 + ty + i) * M + m0 + tx];
    __syncthreads();
    #pragma unroll
    for (int i = 0; i < 32; i += 8)
        dst[(size_t)(m0 + ty + i) * K + k0 + tx] = f2bf(tile[tx][ty + i]);
}

__global__ __launch_bounds__(256) void concat_bias(
    const float* __restrict__ bq, const float* __restrict__ bk,
    const float* __restrict__ bv, float* __restrict__ dst) {
    int i = blockIdx.x * 256 + threadIdx.x;   // 0..3071
    float v = (i < 1024) ? bq[i] : (i < 2048 ? bk[i - 1024] : bv[i - 2048]);
    dst[i] = v;
}

// ---------------------------------------------------------------------------
// V transpose: qkv v-part [(s*B+b)][3072] (+2048+h*64) -> vt[(b*H+h)*64+dh][s]
// ---------------------------------------------------------------------------
__global__ __launch_bounds__(256) void transpose_v(
    const unsigned short* __restrict__ qkv, unsigned short* __restrict__ vt) {
    __shared__ unsigned short t[64][72];
    const int tid = threadIdx.x;
    const int s0 = blockIdx.x * 64;
    const int h  = blockIdx.y;
    const int b  = blockIdx.z;
    #pragma unroll
    for (int i = 0; i < 2; i++) {
        int c = i * 256 + tid;
        int row = c >> 3, off = (c & 7) * 8;
        *(uint4*)&t[row][off] =
            *(const uint4*)(qkv + ((size_t)(s0 + row) * B + b) * QKVS + 2048 + h * 64 + off);
    }
    __syncthreads();
    #pragma unroll
    for (int i = 0; i < 2; i++) {
        int c = i * 256 + tid;
        int dh = c >> 3, off = (c & 7) * 8;
        unsigned short tmp[8];
        #pragma unroll
        for (int j = 0; j < 8; j++) tmp[j] = t[off + j][dh];
        *(uint4*)(vt + ((size_t)((b * H + h) * 64 + dh)) * S + s0 + off) = *(uint4*)tmp;
    }
}

// ---------------------------------------------------------------------------
// LayerNorm: x fp32 [rows][1024] -> out bf16, one block per row
// ---------------------------------------------------------------------------
__global__ __launch_bounds__(256) void ln_kernel(
    const float* __restrict__ x, const float* __restrict__ g,
    const float* __restrict__ b, unsigned short* __restrict__ out) {
    const int row = blockIdx.x;
    const int tid = threadIdx.x;
    float4 v = ((const float4*)(x + (size_t)row * D))[tid];
    float s  = v.x + v.y + v.z + v.w;
    float ss = v.x * v.x + v.y * v.y + v.z * v.z + v.w * v.w;
    #pragma unroll
    for (int o = 32; o > 0; o >>= 1) {
        s  += __shfl_down(s,  o, 64);
        ss += __shfl_down(ss, o, 64);
    }
    __shared__ float red[8];
    __shared__ float mv[2];
    const int wv = tid >> 6, ln = tid & 63;
    if (ln == 0) { red[wv] = s; red[4 + wv] = ss; }
    __syncthreads();
    if (tid == 0) {
        float S2 = red[0] + red[1] + red[2] + red[3];
        float SS = red[4] + red[5] + red[6] + red[7];
        float mean = S2 * (1.0f / D);
        float var  = SS * (1.0f / D) - mean * mean;
        mv[0] = mean;
        mv[1] = rsqrtf(var + 1e-5f);
    }
    __syncthreads();
    const float mean = mv[0], inv = mv[1];
    float4 gv = ((const float4*)g)[tid];
    float4 bv = ((const float4*)b)[tid];
    ushort4 o4;
    o4.x = f2bf((v.x - mean) * inv * gv.x + bv.x);
    o4.y = f2bf((v.y - mean) * inv * gv.y + bv.y);
    o4.z = f2bf((v.z - mean) * inv * gv.z + bv.z);
    o4.w = f2bf((v.w - mean) * inv * gv.w + bv.w);
    ((ushort4*)(out + (size_t)row * D))[tid] = o4;
}

// ---------------------------------------------------------------------------
// bf16 MFMA GEMM: C[N][M] = A[N][K]*B^T, BK=64 (barriers halved per MFMA),
// global_load_lds 16B staging, 128B LDS rows, XOR swizzle c' = c ^ (row&7).
// __launch_bounds__(256,3): ~150 VGPR est -> 3 blocks/CU, LDS 32 KB.
// ---------------------------------------------------------------------------
template <int RELU, int RESID, int OUT_BF16>
__global__ __launch_bounds__(256, 3) void gemm_bt(
    const unsigned short* __restrict__ A,   // [N][K] bf16
    const unsigned short* __restrict__ Bt,  // [M][K] bf16
    const float* __restrict__ bias,         // [M]
    const float* __restrict__ resid,        // [N][M] fp32 (if RESID)
    void* __restrict__ out,                 // [N][M] bf16 or fp32
    int M, int K) {
    __shared__ __align__(16) unsigned short As[128 * 64];   // 16 KB
    __shared__ __align__(16) unsigned short Bs[128 * 64];   // 16 KB

    const int tid  = threadIdx.x;
    const int lane = tid & 63;
    const int wave = tid >> 6;
    const int wr = (wave >> 1) * 64;
    const int wc = (wave & 1) * 64;
    const int n0 = blockIdx.y * 128;
    const int m0 = blockIdx.x * 128;
    const int quad = lane >> 4;
    const int r    = lane & 15;

    floatx4 acc[4][4] = {};

    // staging: wave w owns rows w*32..w*32+31 of As and Bs; 4 glds calls each
    // covering 8 rows (64 lanes x 16B). lane: row = +l>>3, lds chunk = l&7,
    // global chunk = (l&7) ^ (l>>3).
    const int l8  = lane >> 3;
    const int gch = ((lane & 7) ^ l8) * 8;    // global k-offset (elements)
    const unsigned short* gA = A  + (size_t)(n0 + wave * 32 + l8) * K + gch;
    const unsigned short* gB = Bt + (size_t)(m0 + wave * 32 + l8) * K + gch;
    unsigned short* lA = As + wave * 32 * 64;
    unsigned short* lB = Bs + wave * 32 * 64;
    const size_t rowstep = (size_t)8 * K;

    for (int k0 = 0; k0 < K; k0 += 64) {
        __syncthreads();
        #pragma unroll
        for (int c = 0; c < 4; c++) glds16(gA + c * rowstep, lA + c * 512);
        #pragma unroll
        for (int c = 0; c < 4; c++) glds16(gB + c * rowstep, lB + c * 512);
        gA += 64; gB += 64;
        __syncthreads();

        #pragma unroll
        for (int kk = 0; kk < 2; kk++) {
            const int fc = ((kk * 4 + quad) ^ (r & 7)) * 8;   // lds chunk for global chunk kk*4+quad
            bf16x8 af[4], bfr[4];
            #pragma unroll
            for (int i = 0; i < 4; i++)
                af[i] = *(const bf16x8*)&As[(wr + i * 16 + r) * 64 + fc];
            #pragma unroll
            for (int j = 0; j < 4; j++)
                bfr[j] = *(const bf16x8*)&Bs[(wc + j * 16 + r) * 64 + fc];
            #pragma unroll
            for (int i = 0; i < 4; i++)
                #pragma unroll
                for (int j = 0; j < 4; j++)
                    acc[i][j] = __builtin_amdgcn_mfma_f32_16x16x32_bf16(af[i], bfr[j], acc[i][j], 0, 0, 0);
        }
    }

    #pragma unroll
    for (int i = 0; i < 4; i++) {
        #pragma unroll
        for (int j = 0; j < 4; j++) {
            const int row = n0 + wr + i * 16 + quad * 4;
            const int col = m0 + wc + j * 16 + r;
            const float bcol = bias[col];
            #pragma unroll
            for (int rr = 0; rr < 4; rr++) {
                float val = acc[i][j][rr] + bcol;
                if constexpr (RESID) val += resid[(size_t)(row + rr) * M + col];
                if constexpr (RELU)  val = fmaxf(val, 0.0f);
                if constexpr (OUT_BF16)
                    ((unsigned short*)out)[(size_t)(row + rr) * M + col] = f2bf(val);
                else
                    ((float*)out)[(size_t)(row + rr) * M + col] = val;
            }
        }
    }
}

// ---------------------------------------------------------------------------
// MFMA flash attention v4: q-aligned waves (Ps barrier-free), full-tile V
// prefetch (16 loads covered by QK^T), XCD-swizzled grid so all 16 q-tiles of
// one (b,h) share an XCD L2 (K/V resident). q/k read from fused qkv buffer.
// ---------------------------------------------------------------------------
__global__ __launch_bounds__(256, 3) void flash_attn(
    const unsigned short* __restrict__ qkv,
    const unsigned short* __restrict__ vt,
    unsigned short* __restrict__ ctx) {
    constexpr int LQK = 72;
    constexpr int LP  = 136;
    constexpr float SCL = 0.18033688011112042f;  // (1/sqrt(64)) * log2(e)

    __shared__ __align__(16) unsigned short Ks[128 * LQK];  // 18432 B (Qs at init)
    __shared__ __align__(16) unsigned short Ps[128 * LP];   // 34816 B

    const int tid  = threadIdx.x;
    const int lane = tid & 63;
    const int wave = tid >> 6;
    const int quad = lane >> 4;
    const int r    = lane & 15;
    // XCD swizzle: blocks with equal (g, xcd) => same (b,h), same XCD (n%8 rr)
    const int flat = blockIdx.x;
    const int xcd  = flat & 7;
    const int t0   = (flat >> 3) & 15;
    const int bh   = (flat >> 7) * 8 + xcd;
    const int b    = bh >> 4;
    const int h    = bh & 15;
    const int s0   = t0 * 128;
    const int wq0  = wave * 32;

    // ---- stage Q through Ks alias, pull Q B-frags ----
    unsigned short* Qs = Ks;
    #pragma unroll
    for (int i = 0; i < 4; i++) {
        int c = i * 256 + tid;
        int row = c >> 3, off = (c & 7) * 8;
        *(uint4*)&Qs[row * LQK + off] =
            *(const uint4*)(qkv + ((size_t)(s0 + row) * B + b) * QKVS + h * 64 + off);
    }
    __syncthreads();
    bf16x8 qf[2][2];
    #pragma unroll
    for (int j = 0; j < 2; j++)
        #pragma unroll
        for (int kk = 0; kk < 2; kk++)
            qf[j][kk] = *(const bf16x8*)&Qs[(wq0 + j * 16 + r) * LQK + kk * 32 + quad * 8];

    const bf16x8 ones = {(short)0x3F80, (short)0x3F80, (short)0x3F80, (short)0x3F80,
                         (short)0x3F80, (short)0x3F80, (short)0x3F80, (short)0x3F80};

    // ---- prefetch K tile 0 ----
    uint4 kr[4];
    const unsigned short* kbase  = qkv + (size_t)b * QKVS + 1024 + h * 64;  // + row*B*QKVS
    const unsigned short* vtbase = vt + (size_t)((b * H + h) * 64) * S;
    #pragma unroll
    for (int i = 0; i < 4; i++) {
        int c = i * 256 + tid;
        int row = c >> 3, off = (c & 7) * 8;
        kr[i] = *(const uint4*)(kbase + (size_t)row * B * QKVS + off);
    }

    floatx4 acc2[2][4] = {};
    floatx4 accD[2]    = {};

    for (int t = 0; t < S / 128; t++) {
        __syncthreads();   // prev-iter Ks consumers done
        #pragma unroll
        for (int i = 0; i < 4; i++) {
            int c = i * 256 + tid;
            int row = c >> 3, off = (c & 7) * 8;
            *(uint4*)&Ks[row * LQK + off] = kr[i];
        }
        __syncthreads();   // Ks visible

        // full V-tile prefetch: 16 x dwordx4, latency covered by QK^T phase
        const unsigned short* vrow = vtbase + (size_t)r * S + t * 128 + quad * 8;
        uint4 vbuf[4][4];
        #pragma unroll
        for (int ss = 0; ss < 4; ss++)
            #pragma unroll
            for (int jn = 0; jn < 4; jn++)
                vbuf[ss][jn] = *(const uint4*)(vrow + (size_t)(jn * 16) * S + ss * 32);

        if (t + 1 < S / 128) {   // K prefetch for next tile
            const size_t tb = (size_t)(t + 1) * 128;
            #pragma unroll
            for (int i = 0; i < 4; i++) {
                int c = i * 256 + tid;
                int row = c >> 3, off = (c & 7) * 8;
                kr[i] = *(const uint4*)(kbase + (tb + row) * B * QKVS + off);
            }
        }

        // ---- QK^T: 2 q-frags x 8 key-frags; exp2+pack -> Ps ----
        #pragma unroll
        for (int i = 0; i < 8; i++) {
            bf16x8 kf0 = *(const bf16x8*)&Ks[(i * 16 + r) * LQK + quad * 8];
            bf16x8 kf1 = *(const bf16x8*)&Ks[(i * 16 + r) * LQK + 32 + quad * 8];
            #pragma unroll
            for (int j = 0; j < 2; j++) {
                floatx4 sc = {};
                sc = __builtin_amdgcn_mfma_f32_16x16x32_bf16(kf0, qf[j][0], sc, 0, 0, 0);
                sc = __builtin_amdgcn_mfma_f32_16x16x32_bf16(kf1, qf[j][1], sc, 0, 0, 0);
                float p0 = exp2f(sc[0] * SCL);
                float p1 = exp2f(sc[1] * SCL);
                float p2 = exp2f(sc[2] * SCL);
                float p3 = exp2f(sc[3] * SCL);
                uint2 w;
                w.x = pack_bf2_fast(p0, p1);
                w.y = pack_bf2_fast(p2, p3);
                *(uint2*)&Ps[(wq0 + j * 16 + r) * LP + i * 16 + quad * 4] = w;
            }
        }
        // no barrier: waves read back only their own Ps rows (lgkmcnt order)

        // ---- PV + denom ----
        #pragma unroll
        for (int s = 0; s < 4; s++) {
            bf16x8 a2[2];
            #pragma unroll
            for (int j = 0; j < 2; j++)
                a2[j] = *(const bf16x8*)&Ps[(wq0 + j * 16 + r) * LP + s * 32 + quad * 8];
            #pragma unroll
            for (int j = 0; j < 2; j++) {
                #pragma unroll
                for (int jn = 0; jn < 4; jn++)
                    acc2[j][jn] = __builtin_amdgcn_mfma_f32_16x16x32_bf16(
                        a2[j], __builtin_bit_cast(bf16x8, vbuf[s][jn]), acc2[j][jn], 0, 0, 0);
                accD[j] = __builtin_amdgcn_mfma_f32_16x16x32_bf16(a2[j], ones, accD[j], 0, 0, 0);
            }
        }
    }

    float inv[2][4];
    #pragma unroll
    for (int j = 0; j < 2; j++)
        #pragma unroll
        for (int rr = 0; rr < 4; rr++)
            inv[j][rr] = 1.0f / accD[j][rr];

    #pragma unroll
    for (int j = 0; j < 2; j++) {
        #pragma unroll
        for (int jn = 0; jn < 4; jn++) {
            #pragma unroll
            for (int rr = 0; rr < 4; rr++) {
                const int qrow = wq0 + j * 16 + quad * 4 + rr;
                const int dh   = jn * 16 + r;
                ctx[((size_t)(s0 + qrow) * B + b) * D + h * 64 + dh] =
                    f2bf(acc2[j][jn][rr] * inv[j][rr]);
            }
        }
    }
}

// ---------------------------------------------------------------------------
// Launch
// ---------------------------------------------------------------------------
extern "C" void kernel_launch(void* const* d_in, const int* in_sizes, int n_in,
                              void* d_out, int out_size, void* d_ws, size_t ws_size,
                              hipStream_t stream) {
    const float* x    = (const float*)d_in[0];
    const float* ln1g = (const float*)d_in[1];
    const float* ln1b = (const float*)d_in[2];
    const float* ln2g = (const float*)d_in[3];
    const float* ln2b = (const float*)d_in[4];
    const float* Wq   = (const float*)d_in[5];
    const float* bq   = (const float*)d_in[6];
    const float* Wk   = (const float*)d_in[7];
    const float* bk   = (const float*)d_in[8];
    const float* Wv   = (const float*)d_in[9];
    const float* bv   = (const float*)d_in[10];
    const float* Wo   = (const float*)d_in[11];
    const float* bo   = (const float*)d_in[12];
    const float* W1   = (const float*)d_in[13];
    const float* b1   = (const float*)d_in[14];
    const float* W2   = (const float*)d_in[15];
    const float* b2   = (const float*)d_in[16];
    float* out = (float*)d_out;

    char* ws = (char*)d_ws;
    const size_t MB = 1ull << 20;
    unsigned short* wqkvT = (unsigned short*)(ws + 0 * MB);   // [3072][1024] bf16 = 6 MB
    unsigned short* woT   = (unsigned short*)(ws + 6 * MB);   // 2 MB
    unsigned short* w1T   = (unsigned short*)(ws + 8 * MB);   // 8 MB
    unsigned short* w2T   = (unsigned short*)(ws + 16 * MB);  // 8 MB
    unsigned short* h     = (unsigned short*)(ws + 24 * MB);  // 16 MB (reused as h2)
    unsigned short* qkv   = (unsigned short*)(ws + 40 * MB);  // [8192][3072] bf16 = 48 MB
    unsigned short* ctx   = (unsigned short*)(ws + 88 * MB);  // 16 MB
    float*          bqkv  = (float*)(ws + 88 * MB);           // 12 KB, dead before ctx written
    float*          x1    = (float*)(ws + 104 * MB);          // 32 MB (written after vt dead)
    unsigned short* vt    = (unsigned short*)(ws + 104 * MB); // 16 MB, aliases x1 (safe)
    unsigned short* ff1   = qkv;                              // 64 MB region 40..104, qkv+ctx dead
    unsigned short* h2    = h;

    const dim3 tb(32, 8);
    convert_transpose<<<dim3(D / 32, D / 32), tb, 0, stream>>>(Wq, wqkvT, D, D);
    convert_transpose<<<dim3(D / 32, D / 32), tb, 0, stream>>>(Wk, wqkvT + (size_t)D * D, D, D);
    convert_transpose<<<dim3(D / 32, D / 32), tb, 0, stream>>>(Wv, wqkvT + 2 * (size_t)D * D, D, D);
    convert_transpose<<<dim3(D / 32, D / 32), tb, 0, stream>>>(Wo, woT, D, D);
    convert_transpose<<<dim3(F / 32, D / 32), tb, 0, stream>>>(W1, w1T, D, F);
    convert_transpose<<<dim3(D / 32, F / 32), tb, 0, stream>>>(W2, w2T, F, D);
    concat_bias<<<12, 256, 0, stream>>>(bq, bk, bv, bqkv);

    ln_kernel<<<N, 256, 0, stream>>>(x, ln1g, ln1b, h);

    // fused QKV: [8192][1024] x [3072][1024]^T -> qkv [8192][3072]
    gemm_bt<0, 0, 1><<<dim3(3 * D / 128, N / 128), 256, 0, stream>>>(
        h, wqkvT, bqkv, nullptr, qkv, 3 * D, D);

    transpose_v<<<dim3(S / 64, H, B), 256, 0, stream>>>(qkv, vt);

    flash_attn<<<dim3((S / 128) * H * B), 256, 0, stream>>>(qkv, vt, ctx);

    const dim3 g1(D / 128, N / 128);
    gemm_bt<0, 1, 0><<<g1, 256, 0, stream>>>(ctx, woT, bo, x, x1, D, D);

    ln_kernel<<<N, 256, 0, stream>>>(x1, ln2g, ln2b, h2);

    gemm_bt<1, 0, 1><<<dim3(F / 128, N / 128), 256, 0, stream>>>(h2, w1T, b1, nullptr, ff1, F, D);

    gemm_bt<0, 1, 0><<<g1, 256, 0, stream>>>(ff1, w2T, b2, x1, out, D, F);
}

// Round 8
// 588.540 us; speedup vs baseline: 1.2276x; 1.2276x over previous
//
#include <hip/hip_runtime.h>
#include <hip/hip_bf16.h>
#include <stdint.h>

// Problem constants
constexpr int S = 2048;
constexpr int B = 4;
constexpr int D = 1024;
constexpr int H = 16;
constexpr int F = 4096;
constexpr int DH = 64;            // D / H
constexpr int N = S * B;          // 8192 rows
constexpr int QKVS = 3 * D;       // qkv row stride

typedef __attribute__((ext_vector_type(8))) short  bf16x8;
typedef __attribute__((ext_vector_type(4))) float  floatx4;

__device__ __forceinline__ unsigned short f2bf(float f) {
    __hip_bfloat16 h = __float2bfloat16(f);
    return __builtin_bit_cast(unsigned short, h);
}
__device__ __forceinline__ uint32_t pack_bf2_fast(float a, float b) {
    uint32_t ua = __builtin_bit_cast(uint32_t, a) + 0x8000u;
    uint32_t ub = __builtin_bit_cast(uint32_t, b) + 0x8000u;
    return (ua >> 16) | (ub & 0xffff0000u);
}
__device__ __forceinline__ void glds16(const unsigned short* g, unsigned short* l) {
    __builtin_amdgcn_global_load_lds((__attribute__((address_space(1))) void*)(g),
                                     (__attribute__((address_space(3))) void*)(l),
                                     16, 0, 0);
}

// ---------------------------------------------------------------------------
// Weight convert + transpose: src fp32 [K][M] -> dst bf16 [M][K]
// ---------------------------------------------------------------------------
__global__ __launch_bounds__(256) void convert_transpose(
    const float* __restrict__ src, unsigned short* __restrict__ dst, int K, int M) {
    __shared__ float tile[32][33];
    const int m0 = blockIdx.x * 32;
    const int k0 = blockIdx.y * 32;
    const int tx = threadIdx.x;
    const int ty = threadIdx.y;
    #pragma unroll
    for (int i = 0; i < 32; i += 8)
        tile[ty + i][tx] = src[(size_t)(k0 + ty + i) * M + m0 + tx];
    __syncthreads();
    #pragma unroll
    for (int i = 0; i < 32; i += 8)
        dst[(size_t)(m0 + ty + i) * K + k0 + tx] = f2bf(tile[tx][ty + i]);
}

__global__ __launch_bounds__(256) void concat_bias(
    const float* __restrict__ bq, const float* __restrict__ bk,
    const float* __restrict__ bv, float* __restrict__ dst) {
    int i = blockIdx.x * 256 + threadIdx.x;   // 0..3071
    float v = (i < 1024) ? bq[i] : (i < 2048 ? bk[i - 1024] : bv[i - 2048]);
    dst[i] = v;
}

// ---------------------------------------------------------------------------
// V transpose: qkv v-part [(s*B+b)][3072] (+2048+h*64) -> vt[(b*H+h)*64+dh][s]
// ---------------------------------------------------------------------------
__global__ __launch_bounds__(256) void transpose_v(
    const unsigned short* __restrict__ qkv, unsigned short* __restrict__ vt) {
    __shared__ unsigned short t[64][72];
    const int tid = threadIdx.x;
    const int s0 = blockIdx.x * 64;
    const int h  = blockIdx.y;
    const int b  = blockIdx.z;
    #pragma unroll
    for (int i = 0; i < 2; i++) {
        int c = i * 256 + tid;
        int row = c >> 3, off = (c & 7) * 8;
        *(uint4*)&t[row][off] =
            *(const uint4*)(qkv + ((size_t)(s0 + row) * B + b) * QKVS + 2048 + h * 64 + off);
    }
    __syncthreads();
    #pragma unroll
    for (int i = 0; i < 2; i++) {
        int c = i * 256 + tid;
        int dh = c >> 3, off = (c & 7) * 8;
        unsigned short tmp[8];
        #pragma unroll
        for (int j = 0; j < 8; j++) tmp[j] = t[off + j][dh];
        *(uint4*)(vt + ((size_t)((b * H + h) * 64 + dh)) * S + s0 + off) = *(uint4*)tmp;
    }
}

// ---------------------------------------------------------------------------
// LayerNorm: x fp32 [rows][1024] -> out bf16, one block per row
// ---------------------------------------------------------------------------
__global__ __launch_bounds__(256) void ln_kernel(
    const float* __restrict__ x, const float* __restrict__ g,
    const float* __restrict__ b, unsigned short* __restrict__ out) {
    const int row = blockIdx.x;
    const int tid = threadIdx.x;
    float4 v = ((const float4*)(x + (size_t)row * D))[tid];
    float s  = v.x + v.y + v.z + v.w;
    float ss = v.x * v.x + v.y * v.y + v.z * v.z + v.w * v.w;
    #pragma unroll
    for (int o = 32; o > 0; o >>= 1) {
        s  += __shfl_down(s,  o, 64);
        ss += __shfl_down(ss, o, 64);
    }
    __shared__ float red[8];
    __shared__ float mv[2];
    const int wv = tid >> 6, ln = tid & 63;
    if (ln == 0) { red[wv] = s; red[4 + wv] = ss; }
    __syncthreads();
    if (tid == 0) {
        float S2 = red[0] + red[1] + red[2] + red[3];
        float SS = red[4] + red[5] + red[6] + red[7];
        float mean = S2 * (1.0f / D);
        float var  = SS * (1.0f / D) - mean * mean;
        mv[0] = mean;
        mv[1] = rsqrtf(var + 1e-5f);
    }
    __syncthreads();
    const float mean = mv[0], inv = mv[1];
    float4 gv = ((const float4*)g)[tid];
    float4 bv = ((const float4*)b)[tid];
    ushort4 o4;
    o4.x = f2bf((v.x - mean) * inv * gv.x + bv.x);
    o4.y = f2bf((v.y - mean) * inv * gv.y + bv.y);
    o4.z = f2bf((v.z - mean) * inv * gv.z + bv.z);
    o4.w = f2bf((v.w - mean) * inv * gv.w + bv.w);
    ((ushort4*)(out + (size_t)row * D))[tid] = o4;
}

// ---------------------------------------------------------------------------
// bf16 MFMA GEMM: C[N][M] = A[N][K]*B^T, BK=64, global_load_lds 16B staging,
// 128B LDS rows, XOR swizzle c' = c ^ (row&7). (256,3): 3 blocks/CU.
// ---------------------------------------------------------------------------
template <int RELU, int RESID, int OUT_BF16>
__global__ __launch_bounds__(256, 3) void gemm_bt(
    const unsigned short* __restrict__ A,   // [N][K] bf16
    const unsigned short* __restrict__ Bt,  // [M][K] bf16
    const float* __restrict__ bias,         // [M]
    const float* __restrict__ resid,        // [N][M] fp32 (if RESID)
    void* __restrict__ out,                 // [N][M] bf16 or fp32
    int M, int K) {
    __shared__ __align__(16) unsigned short As[128 * 64];   // 16 KB
    __shared__ __align__(16) unsigned short Bs[128 * 64];   // 16 KB

    const int tid  = threadIdx.x;
    const int lane = tid & 63;
    const int wave = tid >> 6;
    const int wr = (wave >> 1) * 64;
    const int wc = (wave & 1) * 64;
    const int n0 = blockIdx.y * 128;
    const int m0 = blockIdx.x * 128;
    const int quad = lane >> 4;
    const int r    = lane & 15;

    floatx4 acc[4][4] = {};

    const int l8  = lane >> 3;
    const int gch = ((lane & 7) ^ l8) * 8;    // global k-offset (elements)
    const unsigned short* gA = A  + (size_t)(n0 + wave * 32 + l8) * K + gch;
    const unsigned short* gB = Bt + (size_t)(m0 + wave * 32 + l8) * K + gch;
    unsigned short* lA = As + wave * 32 * 64;
    unsigned short* lB = Bs + wave * 32 * 64;
    const size_t rowstep = (size_t)8 * K;

    for (int k0 = 0; k0 < K; k0 += 64) {
        __syncthreads();
        #pragma unroll
        for (int c = 0; c < 4; c++) glds16(gA + c * rowstep, lA + c * 512);
        #pragma unroll
        for (int c = 0; c < 4; c++) glds16(gB + c * rowstep, lB + c * 512);
        gA += 64; gB += 64;
        __syncthreads();

        #pragma unroll
        for (int kk = 0; kk < 2; kk++) {
            const int fc = ((kk * 4 + quad) ^ (r & 7)) * 8;
            bf16x8 af[4], bfr[4];
            #pragma unroll
            for (int i = 0; i < 4; i++)
                af[i] = *(const bf16x8*)&As[(wr + i * 16 + r) * 64 + fc];
            #pragma unroll
            for (int j = 0; j < 4; j++)
                bfr[j] = *(const bf16x8*)&Bs[(wc + j * 16 + r) * 64 + fc];
            #pragma unroll
            for (int i = 0; i < 4; i++)
                #pragma unroll
                for (int j = 0; j < 4; j++)
                    acc[i][j] = __builtin_amdgcn_mfma_f32_16x16x32_bf16(af[i], bfr[j], acc[i][j], 0, 0, 0);
        }
    }

    #pragma unroll
    for (int i = 0; i < 4; i++) {
        #pragma unroll
        for (int j = 0; j < 4; j++) {
            const int row = n0 + wr + i * 16 + quad * 4;
            const int col = m0 + wc + j * 16 + r;
            const float bcol = bias[col];
            #pragma unroll
            for (int rr = 0; rr < 4; rr++) {
                float val = acc[i][j][rr] + bcol;
                if constexpr (RESID) val += resid[(size_t)(row + rr) * M + col];
                if constexpr (RELU)  val = fmaxf(val, 0.0f);
                if constexpr (OUT_BF16)
                    ((unsigned short*)out)[(size_t)(row + rr) * M + col] = f2bf(val);
                else
                    ((float*)out)[(size_t)(row + rr) * M + col] = val;
            }
        }
    }
}

// ---------------------------------------------------------------------------
// MFMA flash attention v5: q-aligned waves (Ps barrier-free), V staged into
// LDS via global_load_lds (zero VGPR, drained by the existing barrier — fixes
// round-7's compiler-sunk register prefetch). Vs flat 64x256B with 16B-chunk
// XOR swizzle chunk' = chunk ^ (dh&15): staging stays 256B-coalesced, PV
// ds_read_b128 perfectly bank-uniform. K keeps 1-tile-ahead VGPR prefetch.
// XCD-swizzled grid (FETCH 152->40 MB measured). 1024 blocks = 2 x 512
// resident at 2 blocks/CU -> zero tail.
// ---------------------------------------------------------------------------
__global__ __launch_bounds__(256, 2) void flash_attn(
    const unsigned short* __restrict__ qkv,
    const unsigned short* __restrict__ vt,
    unsigned short* __restrict__ ctx) {
    constexpr int LQK = 72;
    constexpr int LP  = 136;
    constexpr float SCL = 0.18033688011112042f;  // (1/sqrt(64)) * log2(e)

    __shared__ __align__(16) unsigned short Ks[128 * LQK];  // 18432 B (Qs at init)
    __shared__ __align__(16) unsigned short Ps[128 * LP];   // 34816 B
    __shared__ __align__(16) unsigned short Vs[64 * 128];   // 16384 B, flat+swizzled

    const int tid  = threadIdx.x;
    const int lane = tid & 63;
    const int wave = tid >> 6;
    const int quad = lane >> 4;
    const int r    = lane & 15;
    // XCD swizzle: all 16 q-tiles of one (b,h) share an XCD
    const int flat = blockIdx.x;
    const int xcd  = flat & 7;
    const int t0   = (flat >> 3) & 15;
    const int bh   = (flat >> 7) * 8 + xcd;
    const int b    = bh >> 4;
    const int h    = bh & 15;
    const int s0   = t0 * 128;
    const int wq0  = wave * 32;

    // ---- stage Q through Ks alias, pull Q B-frags ----
    unsigned short* Qs = Ks;
    #pragma unroll
    for (int i = 0; i < 4; i++) {
        int c = i * 256 + tid;
        int row = c >> 3, off = (c & 7) * 8;
        *(uint4*)&Qs[row * LQK + off] =
            *(const uint4*)(qkv + ((size_t)(s0 + row) * B + b) * QKVS + h * 64 + off);
    }
    __syncthreads();
    bf16x8 qf[2][2];
    #pragma unroll
    for (int j = 0; j < 2; j++)
        #pragma unroll
        for (int kk = 0; kk < 2; kk++)
            qf[j][kk] = *(const bf16x8*)&Qs[(wq0 + j * 16 + r) * LQK + kk * 32 + quad * 8];

    const bf16x8 ones = {(short)0x3F80, (short)0x3F80, (short)0x3F80, (short)0x3F80,
                         (short)0x3F80, (short)0x3F80, (short)0x3F80, (short)0x3F80};

    // ---- prefetch K tile 0 ----
    uint4 kr[4];
    const unsigned short* kbase  = qkv + (size_t)b * QKVS + 1024 + h * 64;  // + row*B*QKVS
    const unsigned short* vtbase = vt + (size_t)((b * H + h) * 64) * S;
    #pragma unroll
    for (int i = 0; i < 4; i++) {
        int c = i * 256 + tid;
        int row = c >> 3, off = (c & 7) * 8;
        kr[i] = *(const uint4*)(kbase + (size_t)row * B * QKVS + off);
    }

    // V staging constants (per-lane, loop-invariant): call c covers dh rows
    // 4c..4c+3; lane i -> dh = 4c + (i>>4), global chunk = (i&15) ^ (dh&15).
    const int vdh_lo = lane >> 4;          // 0..3

    floatx4 acc2[2][4] = {};
    floatx4 accD[2]    = {};

    for (int t = 0; t < S / 128; t++) {
        __syncthreads();   // prev-iter Ks/Ps/Vs consumers done
        // ---- async V stage for tile t (4 glds16 per wave, 16 total) ----
        {
            const unsigned short* vtt = vtbase + t * 128;
            #pragma unroll
            for (int c4 = 0; c4 < 4; c4++) {
                const int c   = wave * 4 + c4;
                const int dh  = 4 * c + vdh_lo;
                const int gch = (lane & 15) ^ (dh & 15);
                glds16(vtt + (size_t)dh * S + gch * 8, Vs + c * 512);
            }
        }
        // ---- Ks write from kr ----
        #pragma unroll
        for (int i = 0; i < 4; i++) {
            int c = i * 256 + tid;
            int row = c >> 3, off = (c & 7) * 8;
            *(uint4*)&Ks[row * LQK + off] = kr[i];
        }
        __syncthreads();   // drains glds (vmcnt) + ds_writes -> Ks/Vs visible

        if (t + 1 < S / 128) {   // K prefetch for next tile (overlaps compute)
            const size_t tb = (size_t)(t + 1) * 128;
            #pragma unroll
            for (int i = 0; i < 4; i++) {
                int c = i * 256 + tid;
                int row = c >> 3, off = (c & 7) * 8;
                kr[i] = *(const uint4*)(kbase + (tb + row) * B * QKVS + off);
            }
        }

        // ---- QK^T: 2 q-frags x 8 key-frags; exp2+pack -> Ps ----
        #pragma unroll
        for (int i = 0; i < 8; i++) {
            bf16x8 kf0 = *(const bf16x8*)&Ks[(i * 16 + r) * LQK + quad * 8];
            bf16x8 kf1 = *(const bf16x8*)&Ks[(i * 16 + r) * LQK + 32 + quad * 8];
            #pragma unroll
            for (int j = 0; j < 2; j++) {
                floatx4 sc = {};
                sc = __builtin_amdgcn_mfma_f32_16x16x32_bf16(kf0, qf[j][0], sc, 0, 0, 0);
                sc = __builtin_amdgcn_mfma_f32_16x16x32_bf16(kf1, qf[j][1], sc, 0, 0, 0);
                float p0 = exp2f(sc[0] * SCL);
                float p1 = exp2f(sc[1] * SCL);
                float p2 = exp2f(sc[2] * SCL);
                float p3 = exp2f(sc[3] * SCL);
                uint2 w;
                w.x = pack_bf2_fast(p0, p1);
                w.y = pack_bf2_fast(p2, p3);
                *(uint2*)&Ps[(wq0 + j * 16 + r) * LP + i * 16 + quad * 4] = w;
            }
        }
        // no barrier: waves read back only their own Ps rows (lgkmcnt order)

        // ---- PV + denom: B-frags from swizzled Vs ----
        #pragma unroll
        for (int s = 0; s < 4; s++) {
            bf16x8 a2[2];
            #pragma unroll
            for (int j = 0; j < 2; j++)
                a2[j] = *(const bf16x8*)&Ps[(wq0 + j * 16 + r) * LP + s * 32 + quad * 8];
            bf16x8 b2[4];
            #pragma unroll
            for (int jn = 0; jn < 4; jn++)
                b2[jn] = *(const bf16x8*)&Vs[(jn * 16 + r) * 128 + (((s * 4 + quad) ^ r) * 8)];
            #pragma unroll
            for (int j = 0; j < 2; j++) {
                #pragma unroll
                for (int jn = 0; jn < 4; jn++)
                    acc2[j][jn] = __builtin_amdgcn_mfma_f32_16x16x32_bf16(a2[j], b2[jn], acc2[j][jn], 0, 0, 0);
                accD[j] = __builtin_amdgcn_mfma_f32_16x16x32_bf16(a2[j], ones, accD[j], 0, 0, 0);
            }
        }
    }

    float inv[2][4];
    #pragma unroll
    for (int j = 0; j < 2; j++)
        #pragma unroll
        for (int rr = 0; rr < 4; rr++)
            inv[j][rr] = 1.0f / accD[j][rr];

    #pragma unroll
    for (int j = 0; j < 2; j++) {
        #pragma unroll
        for (int jn = 0; jn < 4; jn++) {
            #pragma unroll
            for (int rr = 0; rr < 4; rr++) {
                const int qrow = wq0 + j * 16 + quad * 4 + rr;
                const int dh   = jn * 16 + r;
                ctx[((size_t)(s0 + qrow) * B + b) * D + h * 64 + dh] =
                    f2bf(acc2[j][jn][rr] * inv[j][rr]);
            }
        }
    }
}

// ---------------------------------------------------------------------------
// Launch
// ---------------------------------------------------------------------------
extern "C" void kernel_launch(void* const* d_in, const int* in_sizes, int n_in,
                              void* d_out, int out_size, void* d_ws, size_t ws_size,
                              hipStream_t stream) {
    const float* x    = (const float*)d_in[0];
    const float* ln1g = (const float*)d_in[1];
    const float* ln1b = (const float*)d_in[2];
    const float* ln2g = (const float*)d_in[3];
    const float* ln2b = (const float*)d_in[4];
    const float* Wq   = (const float*)d_in[5];
    const float* bq   = (const float*)d_in[6];
    const float* Wk   = (const float*)d_in[7];
    const float* bk   = (const float*)d_in[8];
    const float* Wv   = (const float*)d_in[9];
    const float* bv   = (const float*)d_in[10];
    const float* Wo   = (const float*)d_in[11];
    const float* bo   = (const float*)d_in[12];
    const float* W1   = (const float*)d_in[13];
    const float* b1   = (const float*)d_in[14];
    const float* W2   = (const float*)d_in[15];
    const float* b2   = (const float*)d_in[16];
    float* out = (float*)d_out;

    char* ws = (char*)d_ws;
    const size_t MB = 1ull << 20;
    unsigned short* wqkvT = (unsigned short*)(ws + 0 * MB);   // [3072][1024] bf16 = 6 MB
    unsigned short* woT   = (unsigned short*)(ws + 6 * MB);   // 2 MB
    unsigned short* w1T   = (unsigned short*)(ws + 8 * MB);   // 8 MB
    unsigned short* w2T   = (unsigned short*)(ws + 16 * MB);  // 8 MB
    unsigned short* h     = (unsigned short*)(ws + 24 * MB);  // 16 MB (reused as h2)
    unsigned short* qkv   = (unsigned short*)(ws + 40 * MB);  // [8192][3072] bf16 = 48 MB
    unsigned short* ctx   = (unsigned short*)(ws + 88 * MB);  // 16 MB
    float*          bqkv  = (float*)(ws + 88 * MB);           // 12 KB, dead before ctx written
    float*          x1    = (float*)(ws + 104 * MB);          // 32 MB (written after vt dead)
    unsigned short* vt    = (unsigned short*)(ws + 104 * MB); // 16 MB, aliases x1 (safe)
    unsigned short* ff1   = qkv;                              // qkv+ctx dead by FFN time
    unsigned short* h2    = h;

    const dim3 tb(32, 8);
    convert_transpose<<<dim3(D / 32, D / 32), tb, 0, stream>>>(Wq, wqkvT, D, D);
    convert_transpose<<<dim3(D / 32, D / 32), tb, 0, stream>>>(Wk, wqkvT + (size_t)D * D, D, D);
    convert_transpose<<<dim3(D / 32, D / 32), tb, 0, stream>>>(Wv, wqkvT + 2 * (size_t)D * D, D, D);
    convert_transpose<<<dim3(D / 32, D / 32), tb, 0, stream>>>(Wo, woT, D, D);
    convert_transpose<<<dim3(F / 32, D / 32), tb, 0, stream>>>(W1, w1T, D, F);
    convert_transpose<<<dim3(D / 32, F / 32), tb, 0, stream>>>(W2, w2T, F, D);
    concat_bias<<<12, 256, 0, stream>>>(bq, bk, bv, bqkv);

    ln_kernel<<<N, 256, 0, stream>>>(x, ln1g, ln1b, h);

    // fused QKV: [8192][1024] x [3072][1024]^T -> qkv [8192][3072]
    gemm_bt<0, 0, 1><<<dim3(3 * D / 128, N / 128), 256, 0, stream>>>(
        h, wqkvT, bqkv, nullptr, qkv, 3 * D, D);

    transpose_v<<<dim3(S / 64, H, B), 256, 0, stream>>>(qkv, vt);

    flash_attn<<<dim3((S / 128) * H * B), 256, 0, stream>>>(qkv, vt, ctx);

    const dim3 g1(D / 128, N / 128);
    gemm_bt<0, 1, 0><<<g1, 256, 0, stream>>>(ctx, woT, bo, x, x1, D, D);

    ln_kernel<<<N, 256, 0, stream>>>(x1, ln2g, ln2b, h2);

    gemm_bt<1, 0, 1><<<dim3(F / 128, N / 128), 256, 0, stream>>>(h2, w1T, b1, nullptr, ff1, F, D);

    gemm_bt<0, 1, 0><<<g1, 256, 0, stream>>>(ff1, w2T, b2, x1, out, D, F);
}

// Round 9
// 546.452 us; speedup vs baseline: 1.3221x; 1.0770x over previous
//
#include <hip/hip_runtime.h>
#include <hip/hip_bf16.h>
#include <stdint.h>

// Problem constants
constexpr int S = 2048;
constexpr int B = 4;
constexpr int D = 1024;
constexpr int H = 16;
constexpr int F = 4096;
constexpr int DH = 64;            // D / H
constexpr int N = S * B;          // 8192 rows
constexpr int QKVS = 3 * D;       // qkv row stride

typedef __attribute__((ext_vector_type(8))) short  bf16x8;
typedef __attribute__((ext_vector_type(4))) float  floatx4;

__device__ __forceinline__ unsigned short f2bf(float f) {
    __hip_bfloat16 h = __float2bfloat16(f);
    return __builtin_bit_cast(unsigned short, h);
}
__device__ __forceinline__ uint32_t pack_bf2_fast(float a, float b) {
    uint32_t ua = __builtin_bit_cast(uint32_t, a) + 0x8000u;
    uint32_t ub = __builtin_bit_cast(uint32_t, b) + 0x8000u;
    return (ua >> 16) | (ub & 0xffff0000u);
}
__device__ __forceinline__ void glds16(const unsigned short* g, unsigned short* l) {
    __builtin_amdgcn_global_load_lds((__attribute__((address_space(1))) void*)(g),
                                     (__attribute__((address_space(3))) void*)(l),
                                     16, 0, 0);
}

// softmax scale folded into q at QKV-GEMM epilogue: (1/sqrt(64)) * log2(e)
constexpr float QSCL = 0.18033688011112042f;

// ---------------------------------------------------------------------------
// Weight convert + transpose: src fp32 [K][M] -> dst bf16 [M][K]
// ---------------------------------------------------------------------------
__global__ __launch_bounds__(256) void convert_transpose(
    const float* __restrict__ src, unsigned short* __restrict__ dst, int K, int M) {
    __shared__ float tile[32][33];
    const int m0 = blockIdx.x * 32;
    const int k0 = blockIdx.y * 32;
    const int tx = threadIdx.x;
    const int ty = threadIdx.y;
    #pragma unroll
    for (int i = 0; i < 32; i += 8)
        tile[ty + i][tx] = src[(size_t)(k0 + ty + i) * M + m0 + tx];
    __syncthreads();
    #pragma unroll
    for (int i = 0; i < 32; i += 8)
        dst[(size_t)(m0 + ty + i) * K + k0 + tx] = f2bf(tile[tx][ty + i]);
}

__global__ __launch_bounds__(256) void concat_bias(
    const float* __restrict__ bq, const float* __restrict__ bk,
    const float* __restrict__ bv, float* __restrict__ dst) {
    int i = blockIdx.x * 256 + threadIdx.x;   // 0..3071
    float v = (i < 1024) ? bq[i] : (i < 2048 ? bk[i - 1024] : bv[i - 2048]);
    dst[i] = v;
}

// ---------------------------------------------------------------------------
// V transpose: qkv v-part [(s*B+b)][3072] (+2048+h*64) -> vt[(b*H+h)*64+dh][s]
// ---------------------------------------------------------------------------
__global__ __launch_bounds__(256) void transpose_v(
    const unsigned short* __restrict__ qkv, unsigned short* __restrict__ vt) {
    __shared__ unsigned short t[64][72];
    const int tid = threadIdx.x;
    const int s0 = blockIdx.x * 64;
    const int h  = blockIdx.y;
    const int b  = blockIdx.z;
    #pragma unroll
    for (int i = 0; i < 2; i++) {
        int c = i * 256 + tid;
        int row = c >> 3, off = (c & 7) * 8;
        *(uint4*)&t[row][off] =
            *(const uint4*)(qkv + ((size_t)(s0 + row) * B + b) * QKVS + 2048 + h * 64 + off);
    }
    __syncthreads();
    #pragma unroll
    for (int i = 0; i < 2; i++) {
        int c = i * 256 + tid;
        int dh = c >> 3, off = (c & 7) * 8;
        unsigned short tmp[8];
        #pragma unroll
        for (int j = 0; j < 8; j++) tmp[j] = t[off + j][dh];
        *(uint4*)(vt + ((size_t)((b * H + h) * 64 + dh)) * S + s0 + off) = *(uint4*)tmp;
    }
}

// ---------------------------------------------------------------------------
// LayerNorm: x fp32 [rows][1024] -> out bf16, one block per row
// ---------------------------------------------------------------------------
__global__ __launch_bounds__(256) void ln_kernel(
    const float* __restrict__ x, const float* __restrict__ g,
    const float* __restrict__ b, unsigned short* __restrict__ out) {
    const int row = blockIdx.x;
    const int tid = threadIdx.x;
    float4 v = ((const float4*)(x + (size_t)row * D))[tid];
    float s  = v.x + v.y + v.z + v.w;
    float ss = v.x * v.x + v.y * v.y + v.z * v.z + v.w * v.w;
    #pragma unroll
    for (int o = 32; o > 0; o >>= 1) {
        s  += __shfl_down(s,  o, 64);
        ss += __shfl_down(ss, o, 64);
    }
    __shared__ float red[8];
    __shared__ float mv[2];
    const int wv = tid >> 6, ln = tid & 63;
    if (ln == 0) { red[wv] = s; red[4 + wv] = ss; }
    __syncthreads();
    if (tid == 0) {
        float S2 = red[0] + red[1] + red[2] + red[3];
        float SS = red[4] + red[5] + red[6] + red[7];
        float mean = S2 * (1.0f / D);
        float var  = SS * (1.0f / D) - mean * mean;
        mv[0] = mean;
        mv[1] = rsqrtf(var + 1e-5f);
    }
    __syncthreads();
    const float mean = mv[0], inv = mv[1];
    float4 gv = ((const float4*)g)[tid];
    float4 bv = ((const float4*)b)[tid];
    ushort4 o4;
    o4.x = f2bf((v.x - mean) * inv * gv.x + bv.x);
    o4.y = f2bf((v.y - mean) * inv * gv.y + bv.y);
    o4.z = f2bf((v.z - mean) * inv * gv.z + bv.z);
    o4.w = f2bf((v.w - mean) * inv * gv.w + bv.w);
    ((ushort4*)(out + (size_t)row * D))[tid] = o4;
}

// ---------------------------------------------------------------------------
// bf16 MFMA GEMM: C[N][M] = A[N][K]*B^T, BK=64, global_load_lds 16B staging,
// 128B LDS rows, XOR swizzle c' = c ^ (row&7). (256,3): 3 blocks/CU.
// QSCALE: multiply cols < 1024 by QSCL (q pre-scaling for flash exp2).
// ---------------------------------------------------------------------------
template <int RELU, int RESID, int OUT_BF16, int QSCALE = 0>
__global__ __launch_bounds__(256, 3) void gemm_bt(
    const unsigned short* __restrict__ A,   // [N][K] bf16
    const unsigned short* __restrict__ Bt,  // [M][K] bf16
    const float* __restrict__ bias,         // [M]
    const float* __restrict__ resid,        // [N][M] fp32 (if RESID)
    void* __restrict__ out,                 // [N][M] bf16 or fp32
    int M, int K) {
    __shared__ __align__(16) unsigned short As[128 * 64];   // 16 KB
    __shared__ __align__(16) unsigned short Bs[128 * 64];   // 16 KB

    const int tid  = threadIdx.x;
    const int lane = tid & 63;
    const int wave = tid >> 6;
    const int wr = (wave >> 1) * 64;
    const int wc = (wave & 1) * 64;
    const int n0 = blockIdx.y * 128;
    const int m0 = blockIdx.x * 128;
    const int quad = lane >> 4;
    const int r    = lane & 15;

    floatx4 acc[4][4] = {};

    const int l8  = lane >> 3;
    const int gch = ((lane & 7) ^ l8) * 8;    // global k-offset (elements)
    const unsigned short* gA = A  + (size_t)(n0 + wave * 32 + l8) * K + gch;
    const unsigned short* gB = Bt + (size_t)(m0 + wave * 32 + l8) * K + gch;
    unsigned short* lA = As + wave * 32 * 64;
    unsigned short* lB = Bs + wave * 32 * 64;
    const size_t rowstep = (size_t)8 * K;

    for (int k0 = 0; k0 < K; k0 += 64) {
        __syncthreads();
        #pragma unroll
        for (int c = 0; c < 4; c++) glds16(gA + c * rowstep, lA + c * 512);
        #pragma unroll
        for (int c = 0; c < 4; c++) glds16(gB + c * rowstep, lB + c * 512);
        gA += 64; gB += 64;
        __syncthreads();

        #pragma unroll
        for (int kk = 0; kk < 2; kk++) {
            const int fc = ((kk * 4 + quad) ^ (r & 7)) * 8;
            bf16x8 af[4], bfr[4];
            #pragma unroll
            for (int i = 0; i < 4; i++)
                af[i] = *(const bf16x8*)&As[(wr + i * 16 + r) * 64 + fc];
            #pragma unroll
            for (int j = 0; j < 4; j++)
                bfr[j] = *(const bf16x8*)&Bs[(wc + j * 16 + r) * 64 + fc];
            #pragma unroll
            for (int i = 0; i < 4; i++)
                #pragma unroll
                for (int j = 0; j < 4; j++)
                    acc[i][j] = __builtin_amdgcn_mfma_f32_16x16x32_bf16(af[i], bfr[j], acc[i][j], 0, 0, 0);
        }
    }

    #pragma unroll
    for (int i = 0; i < 4; i++) {
        #pragma unroll
        for (int j = 0; j < 4; j++) {
            const int row = n0 + wr + i * 16 + quad * 4;
            const int col = m0 + wc + j * 16 + r;
            const float bcol = bias[col];
            const float cscale = (QSCALE && col < 1024) ? QSCL : 1.0f;
            #pragma unroll
            for (int rr = 0; rr < 4; rr++) {
                float val = acc[i][j][rr] + bcol;
                if constexpr (RESID) val += resid[(size_t)(row + rr) * M + col];
                if constexpr (RELU)  val = fmaxf(val, 0.0f);
                if constexpr (QSCALE) val *= cscale;
                if constexpr (OUT_BF16)
                    ((unsigned short*)out)[(size_t)(row + rr) * M + col] = f2bf(val);
                else
                    ((float*)out)[(size_t)(row + rr) * M + col] = val;
            }
        }
    }
}

// ---------------------------------------------------------------------------
// MFMA flash attention v6: 256-q blocks, 4 waves x 64 q-rows (amortizes the
// per-key LDS traffic 2x per q). P pipelined in 32-key chunks through a small
// Pc[256][40] buffer (q-aligned waves -> no barrier, no full-P LDS). V staged
// to LDS via glds16 (swizzled); K via 1-tile-ahead VGPR prefetch. q comes
// pre-scaled by QSCL from the QKV GEMM -> exp2f directly on scores.
// LDS 54 KB -> 2 blocks/CU; grid 512 = exactly resident, zero tail.
// ---------------------------------------------------------------------------
__global__ __launch_bounds__(256, 2) void flash_attn(
    const unsigned short* __restrict__ qkv,
    const unsigned short* __restrict__ vt,
    unsigned short* __restrict__ ctx) {
    constexpr int LQK = 72;   // Ks row stride
    constexpr int LQ  = 72;   // Q staging stride (in smem2), 144B rows (16B-aligned)
    constexpr int LP  = 40;   // Pc row stride (80 B, 16B-aligned)

    __shared__ __align__(16) unsigned short Ks[128 * LQK];   // 18432 B
    __shared__ __align__(16) unsigned short smem2[18432];    // 36864 B: Pc[256*40] + Vs[64*128]
    unsigned short* Pc = smem2;                 // 20480 B
    unsigned short* Vs = smem2 + 256 * LP;      // 16384 B

    const int tid  = threadIdx.x;
    const int lane = tid & 63;
    const int wave = tid >> 6;
    const int quad = lane >> 4;
    const int r    = lane & 15;
    // XCD swizzle: 512 blocks = 64 bh x 8 q-tiles; same bh -> same XCD
    const int flat = blockIdx.x;
    const int xcd  = flat & 7;
    const int t0   = (flat >> 3) & 7;
    const int bh   = (flat >> 6) * 8 + xcd;
    const int b    = bh >> 4;
    const int h    = bh & 15;
    const int s0   = t0 * 256;
    const int wq0  = wave * 64;     // this wave's q-row origin (64 rows)

    // ---- stage Q (256 rows x 64) through smem2, pull 4 q B-frags ----
    #pragma unroll
    for (int i = 0; i < 8; i++) {
        int c = i * 256 + tid;            // 0..2047 chunks of 8 bf16
        int row = c >> 3, off = (c & 7) * 8;
        *(uint4*)&smem2[row * LQ + off] =
            *(const uint4*)(qkv + ((size_t)(s0 + row) * B + b) * QKVS + h * 64 + off);
    }
    __syncthreads();
    bf16x8 qf[4][2];
    #pragma unroll
    for (int j = 0; j < 4; j++)
        #pragma unroll
        for (int kk = 0; kk < 2; kk++)
            qf[j][kk] = *(const bf16x8*)&smem2[(wq0 + j * 16 + r) * LQ + kk * 32 + quad * 8];
    // loop-top barrier (lgkmcnt-drained) protects smem2 reuse as Pc/Vs

    const bf16x8 ones = {(short)0x3F80, (short)0x3F80, (short)0x3F80, (short)0x3F80,
                         (short)0x3F80, (short)0x3F80, (short)0x3F80, (short)0x3F80};

    // ---- prefetch K tile 0 ----
    uint4 kr[4];
    const unsigned short* kbase  = qkv + (size_t)b * QKVS + 1024 + h * 64;  // + row*B*QKVS
    const unsigned short* vtbase = vt + (size_t)((b * H + h) * 64) * S;
    #pragma unroll
    for (int i = 0; i < 4; i++) {
        int c = i * 256 + tid;
        int row = c >> 3, off = (c & 7) * 8;
        kr[i] = *(const uint4*)(kbase + (size_t)row * B * QKVS + off);
    }

    const int vdh_lo = lane >> 4;   // V staging: dh sub-row within call

    floatx4 acc2[4][4] = {};   // [q frag j][dh frag jn]
    floatx4 accD[4]    = {};   // denominators

    for (int t = 0; t < S / 128; t++) {
        __syncthreads();   // prev-iter Ks/Vs/Pc consumers done (incl. prologue Q reads)
        // ---- async V stage (4 glds16/wave, swizzled chunk' = chunk ^ (dh&15)) ----
        {
            const unsigned short* vtt = vtbase + t * 128;
            #pragma unroll
            for (int c4 = 0; c4 < 4; c4++) {
                const int c   = wave * 4 + c4;
                const int dh  = 4 * c + vdh_lo;
                const int gch = (lane & 15) ^ (dh & 15);
                glds16(vtt + (size_t)dh * S + gch * 8, Vs + c * 512);
            }
        }
        // ---- Ks write from kr ----
        #pragma unroll
        for (int i = 0; i < 4; i++) {
            int c = i * 256 + tid;
            int row = c >> 3, off = (c & 7) * 8;
            *(uint4*)&Ks[row * LQK + off] = kr[i];
        }
        __syncthreads();   // drains glds (vmcnt) + ds_writes -> Ks/Vs visible

        if (t + 1 < S / 128) {   // K prefetch for next tile (overlaps compute)
            const size_t tb = (size_t)(t + 1) * 128;
            #pragma unroll
            for (int i = 0; i < 4; i++) {
                int c = i * 256 + tid;
                int row = c >> 3, off = (c & 7) * 8;
                kr[i] = *(const uint4*)(kbase + (tb + row) * B * QKVS + off);
            }
        }

        // ---- per 32-key chunk: QK^T -> exp2 -> Pc -> PV (no barrier) ----
        #pragma unroll
        for (int s = 0; s < 4; s++) {
            #pragma unroll
            for (int ii = 0; ii < 2; ii++) {
                const int krow = (s * 32 + ii * 16 + r) * LQK;
                bf16x8 kf0 = *(const bf16x8*)&Ks[krow + quad * 8];
                bf16x8 kf1 = *(const bf16x8*)&Ks[krow + 32 + quad * 8];
                #pragma unroll
                for (int j = 0; j < 4; j++) {
                    floatx4 sc = {};
                    sc = __builtin_amdgcn_mfma_f32_16x16x32_bf16(kf0, qf[j][0], sc, 0, 0, 0);
                    sc = __builtin_amdgcn_mfma_f32_16x16x32_bf16(kf1, qf[j][1], sc, 0, 0, 0);
                    float p0 = exp2f(sc[0]);
                    float p1 = exp2f(sc[1]);
                    float p2 = exp2f(sc[2]);
                    float p3 = exp2f(sc[3]);
                    uint2 w;
                    w.x = pack_bf2_fast(p0, p1);
                    w.y = pack_bf2_fast(p2, p3);
                    *(uint2*)&Pc[(wq0 + j * 16 + r) * LP + ii * 16 + quad * 4] = w;
                }
            }
            // read back own rows (within-wave lgkmcnt ordering)
            bf16x8 a2[4], b2[4];
            #pragma unroll
            for (int j = 0; j < 4; j++)
                a2[j] = *(const bf16x8*)&Pc[(wq0 + j * 16 + r) * LP + quad * 8];
            #pragma unroll
            for (int jn = 0; jn < 4; jn++)
                b2[jn] = *(const bf16x8*)&Vs[(jn * 16 + r) * 128 + (((s * 4 + quad) ^ r) * 8)];
            #pragma unroll
            for (int j = 0; j < 4; j++) {
                #pragma unroll
                for (int jn = 0; jn < 4; jn++)
                    acc2[j][jn] = __builtin_amdgcn_mfma_f32_16x16x32_bf16(a2[j], b2[jn], acc2[j][jn], 0, 0, 0);
                accD[j] = __builtin_amdgcn_mfma_f32_16x16x32_bf16(a2[j], ones, accD[j], 0, 0, 0);
            }
        }
    }

    #pragma unroll
    for (int j = 0; j < 4; j++) {
        float inv[4];
        #pragma unroll
        for (int rr = 0; rr < 4; rr++) inv[rr] = 1.0f / accD[j][rr];
        #pragma unroll
        for (int jn = 0; jn < 4; jn++) {
            #pragma unroll
            for (int rr = 0; rr < 4; rr++) {
                const int qrow = wq0 + j * 16 + quad * 4 + rr;
                const int dh   = jn * 16 + r;
                ctx[((size_t)(s0 + qrow) * B + b) * D + h * 64 + dh] =
                    f2bf(acc2[j][jn][rr] * inv[rr]);
            }
        }
    }
}

// ---------------------------------------------------------------------------
// Launch
// ---------------------------------------------------------------------------
extern "C" void kernel_launch(void* const* d_in, const int* in_sizes, int n_in,
                              void* d_out, int out_size, void* d_ws, size_t ws_size,
                              hipStream_t stream) {
    const float* x    = (const float*)d_in[0];
    const float* ln1g = (const float*)d_in[1];
    const float* ln1b = (const float*)d_in[2];
    const float* ln2g = (const float*)d_in[3];
    const float* ln2b = (const float*)d_in[4];
    const float* Wq   = (const float*)d_in[5];
    const float* bq   = (const float*)d_in[6];
    const float* Wk   = (const float*)d_in[7];
    const float* bk   = (const float*)d_in[8];
    const float* Wv   = (const float*)d_in[9];
    const float* bv   = (const float*)d_in[10];
    const float* Wo   = (const float*)d_in[11];
    const float* bo   = (const float*)d_in[12];
    const float* W1   = (const float*)d_in[13];
    const float* b1   = (const float*)d_in[14];
    const float* W2   = (const float*)d_in[15];
    const float* b2   = (const float*)d_in[16];
    float* out = (float*)d_out;

    char* ws = (char*)d_ws;
    const size_t MB = 1ull << 20;
    unsigned short* wqkvT = (unsigned short*)(ws + 0 * MB);   // [3072][1024] bf16 = 6 MB
    unsigned short* woT   = (unsigned short*)(ws + 6 * MB);   // 2 MB
    unsigned short* w1T   = (unsigned short*)(ws + 8 * MB);   // 8 MB
    unsigned short* w2T   = (unsigned short*)(ws + 16 * MB);  // 8 MB
    unsigned short* h     = (unsigned short*)(ws + 24 * MB);  // 16 MB (reused as h2)
    unsigned short* qkv   = (unsigned short*)(ws + 40 * MB);  // [8192][3072] bf16 = 48 MB
    unsigned short* ctx   = (unsigned short*)(ws + 88 * MB);  // 16 MB
    float*          bqkv  = (float*)(ws + 88 * MB);           // 12 KB, dead before ctx written
    float*          x1    = (float*)(ws + 104 * MB);          // 32 MB (written after vt dead)
    unsigned short* vt    = (unsigned short*)(ws + 104 * MB); // 16 MB, aliases x1 (safe)
    unsigned short* ff1   = qkv;                              // qkv+ctx dead by FFN time
    unsigned short* h2    = h;

    const dim3 tb(32, 8);
    convert_transpose<<<dim3(D / 32, D / 32), tb, 0, stream>>>(Wq, wqkvT, D, D);
    convert_transpose<<<dim3(D / 32, D / 32), tb, 0, stream>>>(Wk, wqkvT + (size_t)D * D, D, D);
    convert_transpose<<<dim3(D / 32, D / 32), tb, 0, stream>>>(Wv, wqkvT + 2 * (size_t)D * D, D, D);
    convert_transpose<<<dim3(D / 32, D / 32), tb, 0, stream>>>(Wo, woT, D, D);
    convert_transpose<<<dim3(F / 32, D / 32), tb, 0, stream>>>(W1, w1T, D, F);
    convert_transpose<<<dim3(D / 32, F / 32), tb, 0, stream>>>(W2, w2T, F, D);
    concat_bias<<<12, 256, 0, stream>>>(bq, bk, bv, bqkv);

    ln_kernel<<<N, 256, 0, stream>>>(x, ln1g, ln1b, h);

    // fused QKV (q columns pre-scaled by QSCL): [8192][1024] x [3072][1024]^T
    gemm_bt<0, 0, 1, 1><<<dim3(3 * D / 128, N / 128), 256, 0, stream>>>(
        h, wqkvT, bqkv, nullptr, qkv, 3 * D, D);

    transpose_v<<<dim3(S / 64, H, B), 256, 0, stream>>>(qkv, vt);

    flash_attn<<<dim3((S / 256) * H * B), 256, 0, stream>>>(qkv, vt, ctx);

    const dim3 g1(D / 128, N / 128);
    gemm_bt<0, 1, 0><<<g1, 256, 0, stream>>>(ctx, woT, bo, x, x1, D, D);

    ln_kernel<<<N, 256, 0, stream>>>(x1, ln2g, ln2b, h2);

    gemm_bt<1, 0, 1><<<dim3(F / 128, N / 128), 256, 0, stream>>>(h2, w1T, b1, nullptr, ff1, F, D);

    gemm_bt<0, 1, 0><<<g1, 256, 0, stream>>>(ff1, w2T, b2, x1, out, D, F);
}